// Round 2
// baseline (8747.379 us; speedup 1.0000x reference)
//
#include <hip/hip_runtime.h>
#include <cstdint>
#include <cstddef>

#define BD 32
#define TD 4096
#define ID 256
#define OD 256

// f32 constants, computed in f64 and rounded (matches np.exp on f32 within <=1 ulp)
#define A_DEND 0.90483741803595957f   // exp(-1/10)
#define A_SYN  0.81873075307798182f   // exp(-1/5)
#define A_MEM  0.95122942450071402f   // exp(-1/20)
#define TWO_PI_F 6.28318530717958647692f
#define BASE_DTH 62.8318530717958647692f  // 2*pi*10
#define INV256 0.00390625f

#define DOT4(acc, xv, wv)               \
  acc = fmaf((xv).x, (wv).x, acc);      \
  acc = fmaf((xv).y, (wv).y, acc);      \
  acc = fmaf((xv).z, (wv).z, acc);      \
  acc = fmaf((xv).w, (wv).w, acc);

// ---------------------------------------------------------------------------
// Phase A: weights-in-LDS, R=8 rows x C=2 o-cols per thread.
// LDS instr count scales as (R+7C)/(RC): 4.5 (old R=2,C=1) -> 1.375 (3.3x
// fewer ds_read_b128), moving the bound from the LDS pipe (~9.4 cyc/b128
// measured) to the fmac floor (~765 us/SIMD).
// Block = 512 threads, 16 o-cols, 2048 m-rows in 4 passes of 512 rows;
// x streamed in k-chunks of 8 (double-buffered, 68-float mg-stride keeps the
// 8-distinct-row reads conflict-free; weight reads <=2-way = free).
// Per-output accumulation order (k ascending, DOT4 chain) and epilogue are
// bit-identical to the previous passing kernel.
// ---------------------------------------------------------------------------

#define WSTR 260              // weight row stride (floats)
#define XMGSTR 68             // per-mg stride (floats): banks 4*mg -> conflict-free
#define XBUFF (64 * XMGSTR)   // 4352 floats per chunk buffer

__global__ __launch_bounds__(512, 1)
void proj_kernel(const float* __restrict__ x,
                 const float* __restrict__ Ws,
                 const float* __restrict__ Wb,
                 const float* __restrict__ Wa,
                 float* __restrict__ soma_ws,
                 float* __restrict__ u_ws) {
  #pragma clang fp contract(off)
  __shared__ float wl[112 * WSTR];   // 116,480 B
  __shared__ float xs[2 * XBUFF];    //  34,816 B   (total 151,296 <= 160 KiB)

  const int tid = threadIdx.x;
  // XCD-chunked bijective swizzle over the 16x64 grid
  const int lin = (int)blockIdx.x + ((int)blockIdx.y << 4);   // 0..1023
  const int swz = ((lin & 7) << 7) + (lin >> 3);
  const int o0  = (swz & 15) << 4;
  const int by  = swz >> 4;                                   // 0..63

  // ---- stage weights: rows [0..15]=Ws, [16..79]=Wb(nb=0..3), [80..111]=Wa ----
  for (int rep = 0; rep < 14; ++rep) {
    int f = (rep << 9) + tid;          // float4 index 0..7167
    int r = f >> 6;                    // 0..111
    int c = (f & 63) << 2;             // float col 0..252
    const float* src;
    if (r < 16) {
      src = Ws + (((size_t)(o0 + r)) << 8);
    } else if (r < 80) {
      src = Wb + (((size_t)((((r - 16) >> 4) << 8) + o0 + (r & 15))) << 8);
    } else {
      src = Wa + (((size_t)((((r - 80) >> 4) << 8) + o0 + (r & 15))) << 8);
    }
    *(float4*)(&wl[r * WSTR + c]) = *(const float4*)(src + c);
  }

  const int oo = tid & 7;         // owns o-cols o0+2oo and o0+2oo+1
  const int mg = tid >> 3;        // 0..63: rows mg*8..mg*8+7 of the 512-row pass
  const float* wpp[7];
  #pragma unroll
  for (int p = 0; p < 7; ++p) wpp[p] = wl + (((p << 4) + (oo << 1)) * WSTR);

  // x staging map: chunk = 512 rows x 8 floats = 1024 float4; thread moves 2
  const int row0 = tid >> 1;             // 0..255 (also handles row0+256)
  const int cc   = (tid & 1) << 2;       // 0 or 4
  const int d0   = (row0 >> 3) * XMGSTR + (row0 & 7) * 8 + cc;
  const int d1   = ((row0 >> 3) + 32) * XMGSTR + (row0 & 7) * 8 + cc;

  const size_t trow0 = ((size_t)by) << 11;     // first m-row of this block

  // initial stage: (pass 0, k0 = 0) -> buf 0
  {
    float4 a = *(const float4*)(x + (trow0 + row0) * ID + cc);
    float4 b = *(const float4*)(x + (trow0 + row0 + 256) * ID + cc);
    *(float4*)(&xs[d0]) = a;
    *(float4*)(&xs[d1]) = b;
  }
  __syncthreads();

  for (int pass = 0; pass < 4; ++pass) {
    float acc[7][16];
    #pragma unroll
    for (int p = 0; p < 7; ++p) {
      #pragma unroll
      for (int j = 0; j < 16; ++j) acc[p][j] = 0.f;
    }

    for (int ck = 0; ck < 32; ++ck) {
      const int k0 = ck << 3;
      // T14 issue-early: next chunk global->reg before compute
      float4 pa = {0.f, 0.f, 0.f, 0.f}, pb = {0.f, 0.f, 0.f, 0.f};
      const bool hn = !(pass == 3 && ck == 31);
      if (hn) {
        const int cn = (pass << 5) + ck + 1;           // global chunk 1..127
        const size_t rb = trow0 + ((size_t)(cn >> 5) << 9);
        const int kn = (cn & 31) << 3;
        pa = *(const float4*)(x + (rb + row0) * ID + kn + cc);
        pb = *(const float4*)(x + (rb + row0 + 256) * ID + kn + cc);
      }
      // compute on buf = ck&1 (global chunk parity == ck parity)
      const float* xb = xs + ((ck & 1) ? XBUFF : 0) + mg * XMGSTR;
      #pragma unroll
      for (int q = 0; q < 2; ++q) {
        float4 xv[8];
        #pragma unroll
        for (int r = 0; r < 8; ++r) xv[r] = *(const float4*)(xb + r * 8 + (q << 2));
        const int ko = k0 + (q << 2);
        #pragma unroll
        for (int p = 0; p < 7; ++p) {
          float4 w0 = *(const float4*)(wpp[p] + ko);
          float4 w1 = *(const float4*)(wpp[p] + WSTR + ko);
          #pragma unroll
          for (int r = 0; r < 8; ++r) {
            DOT4(acc[p][r], xv[r], w0)
            DOT4(acc[p][8 + r], xv[r], w1)
          }
        }
      }
      // write-late into the other buffer, one barrier per chunk
      if (hn) {
        float* d = xs + ((ck & 1) ? 0 : XBUFF);
        *(float4*)(d + d0) = pa;
        *(float4*)(d + d1) = pb;
      }
      __syncthreads();
    }

    // epilogue: identical expressions/roundings to the previous passing kernel
    const size_t rbase = trow0 + ((size_t)pass << 9) + ((size_t)mg << 3);
    const int ocol = o0 + (oo << 1);
    #pragma unroll
    for (int r = 0; r < 8; ++r) {
      const size_t off = (rbase + r) * OD + ocol;
      float bm0 = ((fmaxf(acc[1][r], 0.f) + fmaxf(acc[2][r], 0.f)) +
                   (fmaxf(acc[3][r], 0.f) + fmaxf(acc[4][r], 0.f))) * 0.25f;
      float am0 = (fmaxf(acc[5][r], 0.f) + fmaxf(acc[6][r], 0.f)) * 0.5f;
      float bm1 = ((fmaxf(acc[1][8 + r], 0.f) + fmaxf(acc[2][8 + r], 0.f)) +
                   (fmaxf(acc[3][8 + r], 0.f) + fmaxf(acc[4][8 + r], 0.f))) * 0.25f;
      float am1 = (fmaxf(acc[5][8 + r], 0.f) + fmaxf(acc[6][8 + r], 0.f)) * 0.5f;
      float2 sv = {acc[0][r], acc[0][8 + r]};
      float2 uv = {bm0 + am0, bm1 + am1};
      *(float2*)(soma_ws + off) = sv;
      *(float2*)(u_ws + off)    = uv;
    }
  }
}

// ---------------------------------------------------------------------------
// Phase B: sequential LIF + Kuramoto. Re-geometry only: 4 blocks x 512
// threads; wave w owns b = blockIdx*8 + w -> 2 independent b-chains per SIMD
// fill each other's dependency stalls (measured 806 cyc/t vs ~290 issue-min
// for a lone wave). Per-wave math is bit-identical (same lanes, same DPP
// reduction, same op order); no LDS, no barriers.
// ---------------------------------------------------------------------------

#define DPP_ADD(v, ctrl, rm, bm, bc)                                          \
  v += __builtin_bit_cast(float, __builtin_amdgcn_update_dpp(                 \
           0, __builtin_bit_cast(int, v), ctrl, rm, bm, bc));

__device__ __forceinline__ float wave_sum64(float v) {
  DPP_ADD(v, 0x111, 0xf, 0xf, true)    // row_shr:1
  DPP_ADD(v, 0x112, 0xf, 0xf, true)    // row_shr:2
  DPP_ADD(v, 0x114, 0xf, 0xf, true)    // row_shr:4
  DPP_ADD(v, 0x118, 0xf, 0xf, true)    // row_shr:8
  DPP_ADD(v, 0x142, 0xa, 0xf, false)   // row_bcast:15 -> rows 1,3
  DPP_ADD(v, 0x143, 0xc, 0xf, false)   // row_bcast:31 -> rows 2,3
  return __builtin_bit_cast(float, __builtin_amdgcn_readlane(__builtin_bit_cast(int, v), 63));
}

#define PROCESS4(TBASE)                                                       \
  _Pragma("unroll")                                                           \
  for (int i = 0; i < 4; ++i) {                                               \
    const int t = (TBASE) + i;                                                \
    const float* sv = &cs[i].x;                                               \
    const float* uv = &cu[i].x;                                               \
    float spk[4], cc[4], ss[4];                                               \
    _Pragma("unroll")                                                         \
    for (int j = 0; j < 4; ++j) {                                             \
      float t1 = A_DEND * dend[j];                                            \
      float t2 = bD * uv[j];                                                  \
      dend[j] = t1 + t2;                                                      \
      float drive = sv[j] + 0.5f * dend[j];                                   \
      syn[j] = (A_SYN * syn[j]) + drive;                                      \
      mem[j] = (A_MEM * mem[j]) + syn[j];                                     \
      float v = mem[j] - 1.0f;                                                \
      float sp = (v > 0.0f) ? 1.0f : 0.0f;                                    \
      mem[j] = mem[j] - sp;                                                   \
      spk[j] = sp;                                                            \
      cc[j] = __cosf(th[j]);                                                  \
      ss[j] = __sinf(th[j]);                                                  \
    }                                                                         \
    float csum = (cc[0] + cc[1]) + (cc[2] + cc[3]);                           \
    float ssum = (ss[0] + ss[1]) + (ss[2] + ss[3]);                           \
    float cS = wave_sum64(csum);                                              \
    float sS = wave_sum64(ssum);                                              \
    _Pragma("unroll")                                                         \
    for (int j = 0; j < 4; ++j) {                                             \
      float coup = (sS * cc[j] - cS * ss[j]) * INV256;                        \
      float dth = (BASE_DTH + coup) + spk[j];                                 \
      th[j] = th[j] + 0.001f * dth;                                           \
      th[j] = (th[j] >= TWO_PI_F) ? (th[j] - TWO_PI_F) : th[j];               \
    }                                                                         \
    float4 so = {spk[0], spk[1], spk[2], spk[3]};                             \
    float4 po = {th[0], th[1], th[2], th[3]};                                 \
    float4 mo = {mem[0], mem[1], mem[2], mem[3]};                             \
    Os[(size_t)t * 64] = so;                                                  \
    Op[(size_t)t * 64] = po;                                                  \
    Om[(size_t)t * 64] = mo;                                                  \
  }

__global__ __launch_bounds__(512, 1)
void dyn_kernel(const float* __restrict__ soma_ws,
                const float* __restrict__ u_ws,
                float* __restrict__ out) {
  // Match numpy's per-op rounding: no mul+add fusion except explicit fmaf.
  #pragma clang fp contract(off)
  const int b = (int)blockIdx.x * 8 + ((int)threadIdx.x >> 6);  // wave -> batch
  const int l = threadIdx.x & 63;

  const size_t base4 = ((size_t)b << 18) + l;        // float4 units
  const float4* S = (const float4*)soma_ws + base4;
  const float4* U = (const float4*)u_ws + base4;
  float4* Os = (float4*)out + base4;                 // spikes
  float4* Op = Os + ((size_t)1 << 23);               // phases
  float4* Om = Op + ((size_t)1 << 23);               // membrane

  float dend[4] = {0.f, 0.f, 0.f, 0.f};
  float syn[4]  = {0.f, 0.f, 0.f, 0.f};
  float mem[4]  = {0.f, 0.f, 0.f, 0.f};
  float th[4]   = {0.f, 0.f, 0.f, 0.f};

  const float bD = 1.0f - A_DEND;   // exact (Sterbenz)

  float4 As[4], Au[4], Bs[4], Bu[4];
  #pragma unroll
  for (int i = 0; i < 4; ++i) { As[i] = S[(size_t)i * 64];       Au[i] = U[(size_t)i * 64]; }
  #pragma unroll
  for (int i = 0; i < 4; ++i) { Bs[i] = S[(size_t)(4 + i) * 64]; Bu[i] = U[(size_t)(4 + i) * 64]; }

  for (int t8 = 0; t8 < TD / 8; ++t8) {
    float4 cs[4], cu[4];
    #pragma unroll
    for (int i = 0; i < 4; ++i) { cs[i] = As[i]; cu[i] = Au[i]; }
    if (t8 < TD / 8 - 1) {         // refill A with chunk 2*t8+2
      #pragma unroll
      for (int i = 0; i < 4; ++i) {
        As[i] = S[(size_t)((t8 << 3) + 8 + i) * 64];
        Au[i] = U[(size_t)((t8 << 3) + 8 + i) * 64];
      }
    }
    PROCESS4((t8 << 3));
    #pragma unroll
    for (int i = 0; i < 4; ++i) { cs[i] = Bs[i]; cu[i] = Bu[i]; }
    if (t8 < TD / 8 - 1) {         // refill B with chunk 2*t8+3
      #pragma unroll
      for (int i = 0; i < 4; ++i) {
        Bs[i] = S[(size_t)((t8 << 3) + 12 + i) * 64];
        Bu[i] = U[(size_t)((t8 << 3) + 12 + i) * 64];
      }
    }
    PROCESS4((t8 << 3) + 4);
  }
}

// ---------------------------------------------------------------------------

extern "C" void kernel_launch(void* const* d_in, const int* in_sizes, int n_in,
                              void* d_out, int out_size, void* d_ws, size_t ws_size,
                              hipStream_t stream) {
  const float* x  = (const float*)d_in[0];
  const float* Ws = (const float*)d_in[1];
  const float* Wb = (const float*)d_in[2];
  const float* Wa = (const float*)d_in[3];

  float* soma_ws = (float*)d_ws;
  float* u_ws    = soma_ws + (size_t)BD * TD * OD;   // +33554432 floats
  float* out     = (float*)d_out;

  dim3 gA(16, 64, 1);   // 16 o-groups x 64 m-ranges (2048 rows each, 4 passes)
  proj_kernel<<<gA, 512, 0, stream>>>(x, Ws, Wb, Wa, soma_ws, u_ws);
  dyn_kernel<<<4, 512, 0, stream>>>(soma_ws, u_ws, out);
}

// Round 3
// 6695.544 us; speedup vs baseline: 1.3064x; 1.3064x over previous
//
#include <hip/hip_runtime.h>
#include <cstdint>
#include <cstddef>

#define BD 32
#define TD 4096
#define ID 256
#define OD 256

// f32 constants, computed in f64 and rounded (matches np.exp on f32 within <=1 ulp)
#define A_DEND 0.90483741803595957f   // exp(-1/10)
#define A_SYN  0.81873075307798182f   // exp(-1/5)
#define A_MEM  0.95122942450071402f   // exp(-1/20)
#define TWO_PI_F 6.28318530717958647692f
#define BASE_DTH 62.8318530717958647692f  // 2*pi*10
#define INV256 0.00390625f

#define DOT4(acc, xv, wv)               \
  acc = fmaf((xv).x, (wv).x, acc);      \
  acc = fmaf((xv).y, (wv).y, acc);      \
  acc = fmaf((xv).z, (wv).z, acc);      \
  acc = fmaf((xv).w, (wv).w, acc);

// ---------------------------------------------------------------------------
// Phase A v3: wave-uniform o-column; weights via scalar/broadcast loads.
// Block = 512 thr = 8 waves; wave w owns o = blockIdx.y*8 + w (uniform ->
// readfirstlane -> s_load'able). Lane owns rows l+64r (r=0..7) of the block's
// 512-row range. LDS holds ONLY x: 2 bufs x (4 k4-planes x 512 rows x float4)
// = 64 KB, double-buffered in k-chunks of 16. All ds offsets are compile-time
// immediates off a single lane*16 base. LDS pipe: 1 b128 per 28 fmac
// (~513 us/CU) < fmac issue floor (~765 us/SIMD) -> VALU-bound.
// Worst-case VGPR ~100 (acc 56 + xv + px) -> no spill even at a 128 budget;
// 16 waves/CU if <=128. Accumulation order (k-ascending fmaf) and epilogue
// expressions identical to the round-1 passing kernel -> bit-identical.
// ---------------------------------------------------------------------------

#define WLOAD(dst, kq) {                               \
  dst[0] = *(const float4*)(wp0 + ((kq) << 2));        \
  dst[1] = *(const float4*)(wp1 + ((kq) << 2));        \
  dst[2] = *(const float4*)(wp2 + ((kq) << 2));        \
  dst[3] = *(const float4*)(wp3 + ((kq) << 2));        \
  dst[4] = *(const float4*)(wp4 + ((kq) << 2));        \
  dst[5] = *(const float4*)(wp5 + ((kq) << 2));        \
  dst[6] = *(const float4*)(wp6 + ((kq) << 2)); }

#define K4SEC(BUF, Q, W) {                             \
  _Pragma("unroll")                                    \
  for (int r = 0; r < 8; ++r) {                        \
    float4 xv = xsv[(BUF) * 2048 + (Q) * 512 + (r << 6) + l]; \
    DOT4(acc[0][r], xv, W[0])                          \
    DOT4(acc[1][r], xv, W[1])                          \
    DOT4(acc[2][r], xv, W[2])                          \
    DOT4(acc[3][r], xv, W[3])                          \
    DOT4(acc[4][r], xv, W[4])                          \
    DOT4(acc[5][r], xv, W[5])                          \
    DOT4(acc[6][r], xv, W[6])                          \
  } }

// One barrier per chunk: reads hit buf[CK&1]; writes go to the other buffer,
// whose readers all passed the previous barrier (round-1-proven scheme).
#define CHUNK(CK, BUF) {                               \
  float4 px0, px1, px2, px3;                           \
  const bool hn = (CK) < 15;                           \
  if (hn) {                                            \
    px0 = xrow4[(((CK) + 1) << 2) + 0];                \
    px1 = xrow4[(((CK) + 1) << 2) + 1];                \
    px2 = xrow4[(((CK) + 1) << 2) + 2];                \
    px3 = xrow4[(((CK) + 1) << 2) + 3];                \
  }                                                    \
  WLOAD(wO, ((CK) << 2) + 1)                           \
  K4SEC(BUF, 0, wE)                                    \
  WLOAD(wE, ((CK) << 2) + 2)                           \
  K4SEC(BUF, 1, wO)                                    \
  WLOAD(wO, ((CK) << 2) + 3)                           \
  K4SEC(BUF, 2, wE)                                    \
  WLOAD(wE, (((CK) << 2) + 4 > 63) ? 63 : (((CK) << 2) + 4)) \
  K4SEC(BUF, 3, wO)                                    \
  if (hn) {                                            \
    xsw[((BUF) ^ 1) * 2048 + 0 * 512 + tid] = px0;     \
    xsw[((BUF) ^ 1) * 2048 + 1 * 512 + tid] = px1;     \
    xsw[((BUF) ^ 1) * 2048 + 2 * 512 + tid] = px2;     \
    xsw[((BUF) ^ 1) * 2048 + 3 * 512 + tid] = px3;     \
  }                                                    \
  __syncthreads();                                     \
}

__global__ __launch_bounds__(512, 2)
void proj_kernel(const float* __restrict__ x,
                 const float* __restrict__ Ws,
                 const float* __restrict__ Wb,
                 const float* __restrict__ Wa,
                 float* __restrict__ soma_ws,
                 float* __restrict__ u_ws) {
  #pragma clang fp contract(off)
  __shared__ float4 xs[2 * 2048];          // 64 KB -> 2 blocks/CU
  const float4* xsv = xs;
  float4* xsw = xs;

  const int tid = threadIdx.x;
  const int l   = tid & 63;
  const int wid = tid >> 6;                       // 0..7
  const int m0  = (int)blockIdx.x << 9;           // 512 rows per block
  const int o   = ((int)blockIdx.y << 3) + wid;   // wave-uniform
  const int o_u = __builtin_amdgcn_readfirstlane(o);

  const float* wp0 = Ws + ((size_t)o_u << 8);
  const float* wp1 = Wb + ((size_t)(0 * OD + o_u) << 8);
  const float* wp2 = Wb + ((size_t)(1 * OD + o_u) << 8);
  const float* wp3 = Wb + ((size_t)(2 * OD + o_u) << 8);
  const float* wp4 = Wb + ((size_t)(3 * OD + o_u) << 8);
  const float* wp5 = Wa + ((size_t)(0 * OD + o_u) << 8);
  const float* wp6 = Wa + ((size_t)(1 * OD + o_u) << 8);

  // per-thread x row pointer (thread tid stages row m0+tid, 64 B per chunk)
  const float4* xrow4 = (const float4*)(x + ((size_t)(m0 + tid) << 8));

  // stage chunk 0 into buf 0
  {
    float4 a0 = xrow4[0], a1 = xrow4[1], a2 = xrow4[2], a3 = xrow4[3];
    xsw[0 * 512 + tid] = a0;
    xsw[1 * 512 + tid] = a1;
    xsw[2 * 512 + tid] = a2;
    xsw[3 * 512 + tid] = a3;
  }

  float4 wE[7], wO[7];
  WLOAD(wE, 0)

  float acc[7][8];
  #pragma unroll
  for (int p = 0; p < 7; ++p) {
    #pragma unroll
    for (int r = 0; r < 8; ++r) acc[p][r] = 0.f;
  }

  __syncthreads();

  for (int ck2 = 0; ck2 < 8; ++ck2) {
    const int ck = ck2 << 1;
    CHUNK(ck, 0)
    CHUNK(ck + 1, 1)
  }

  // epilogue: identical expressions/roundings to the round-1 passing kernel
  #pragma unroll
  for (int r = 0; r < 8; ++r) {
    const size_t off = ((size_t)(m0 + l + (r << 6)) << 8) + o;
    float bm = ((fmaxf(acc[1][r], 0.f) + fmaxf(acc[2][r], 0.f)) +
                (fmaxf(acc[3][r], 0.f) + fmaxf(acc[4][r], 0.f))) * 0.25f;
    float am = (fmaxf(acc[5][r], 0.f) + fmaxf(acc[6][r], 0.f)) * 0.5f;
    soma_ws[off] = acc[0][r];
    u_ws[off]    = bm + am;
  }
}

// ---------------------------------------------------------------------------
// Phase B: sequential LIF + Kuramoto. 4 blocks x 512 threads; wave w owns
// b = blockIdx*8 + w -> 2 independent b-chains per SIMD fill each other's
// dependency stalls. Round 2's regression was register spill (needs ~140
// VGPRs, budget landed at 128); __launch_bounds__(512, 2) pins the cap at
// 256 -> no spill. Per-wave math bit-identical (same lanes, same DPP
// reduction, same op order); no LDS, no barriers.
// ---------------------------------------------------------------------------

#define DPP_ADD(v, ctrl, rm, bm, bc)                                          \
  v += __builtin_bit_cast(float, __builtin_amdgcn_update_dpp(                 \
           0, __builtin_bit_cast(int, v), ctrl, rm, bm, bc));

__device__ __forceinline__ float wave_sum64(float v) {
  DPP_ADD(v, 0x111, 0xf, 0xf, true)    // row_shr:1
  DPP_ADD(v, 0x112, 0xf, 0xf, true)    // row_shr:2
  DPP_ADD(v, 0x114, 0xf, 0xf, true)    // row_shr:4
  DPP_ADD(v, 0x118, 0xf, 0xf, true)    // row_shr:8
  DPP_ADD(v, 0x142, 0xa, 0xf, false)   // row_bcast:15 -> rows 1,3
  DPP_ADD(v, 0x143, 0xc, 0xf, false)   // row_bcast:31 -> rows 2,3
  return __builtin_bit_cast(float, __builtin_amdgcn_readlane(__builtin_bit_cast(int, v), 63));
}

#define PROCESS4(TBASE)                                                       \
  _Pragma("unroll")                                                           \
  for (int i = 0; i < 4; ++i) {                                               \
    const int t = (TBASE) + i;                                                \
    const float* sv = &cs[i].x;                                               \
    const float* uv = &cu[i].x;                                               \
    float spk[4], cc[4], ss[4];                                               \
    _Pragma("unroll")                                                         \
    for (int j = 0; j < 4; ++j) {                                             \
      float t1 = A_DEND * dend[j];                                            \
      float t2 = bD * uv[j];                                                  \
      dend[j] = t1 + t2;                                                      \
      float drive = sv[j] + 0.5f * dend[j];                                   \
      syn[j] = (A_SYN * syn[j]) + drive;                                      \
      mem[j] = (A_MEM * mem[j]) + syn[j];                                     \
      float v = mem[j] - 1.0f;                                                \
      float sp = (v > 0.0f) ? 1.0f : 0.0f;                                    \
      mem[j] = mem[j] - sp;                                                   \
      spk[j] = sp;                                                            \
      cc[j] = __cosf(th[j]);                                                  \
      ss[j] = __sinf(th[j]);                                                  \
    }                                                                         \
    float csum = (cc[0] + cc[1]) + (cc[2] + cc[3]);                           \
    float ssum = (ss[0] + ss[1]) + (ss[2] + ss[3]);                           \
    float cS = wave_sum64(csum);                                              \
    float sS = wave_sum64(ssum);                                              \
    _Pragma("unroll")                                                         \
    for (int j = 0; j < 4; ++j) {                                             \
      float coup = (sS * cc[j] - cS * ss[j]) * INV256;                        \
      float dth = (BASE_DTH + coup) + spk[j];                                 \
      th[j] = th[j] + 0.001f * dth;                                           \
      th[j] = (th[j] >= TWO_PI_F) ? (th[j] - TWO_PI_F) : th[j];               \
    }                                                                         \
    float4 so = {spk[0], spk[1], spk[2], spk[3]};                             \
    float4 po = {th[0], th[1], th[2], th[3]};                                 \
    float4 mo = {mem[0], mem[1], mem[2], mem[3]};                             \
    Os[(size_t)t * 64] = so;                                                  \
    Op[(size_t)t * 64] = po;                                                  \
    Om[(size_t)t * 64] = mo;                                                  \
  }

__global__ __launch_bounds__(512, 2)
void dyn_kernel(const float* __restrict__ soma_ws,
                const float* __restrict__ u_ws,
                float* __restrict__ out) {
  // Match numpy's per-op rounding: no mul+add fusion except explicit fmaf.
  #pragma clang fp contract(off)
  const int b = (int)blockIdx.x * 8 + ((int)threadIdx.x >> 6);  // wave -> batch
  const int l = threadIdx.x & 63;

  const size_t base4 = ((size_t)b << 18) + l;        // float4 units
  const float4* S = (const float4*)soma_ws + base4;
  const float4* U = (const float4*)u_ws + base4;
  float4* Os = (float4*)out + base4;                 // spikes
  float4* Op = Os + ((size_t)1 << 23);               // phases
  float4* Om = Op + ((size_t)1 << 23);               // membrane

  float dend[4] = {0.f, 0.f, 0.f, 0.f};
  float syn[4]  = {0.f, 0.f, 0.f, 0.f};
  float mem[4]  = {0.f, 0.f, 0.f, 0.f};
  float th[4]   = {0.f, 0.f, 0.f, 0.f};

  const float bD = 1.0f - A_DEND;   // exact (Sterbenz)

  float4 As[4], Au[4], Bs[4], Bu[4];
  #pragma unroll
  for (int i = 0; i < 4; ++i) { As[i] = S[(size_t)i * 64];       Au[i] = U[(size_t)i * 64]; }
  #pragma unroll
  for (int i = 0; i < 4; ++i) { Bs[i] = S[(size_t)(4 + i) * 64]; Bu[i] = U[(size_t)(4 + i) * 64]; }

  for (int t8 = 0; t8 < TD / 8; ++t8) {
    float4 cs[4], cu[4];
    #pragma unroll
    for (int i = 0; i < 4; ++i) { cs[i] = As[i]; cu[i] = Au[i]; }
    if (t8 < TD / 8 - 1) {         // refill A with chunk 2*t8+2
      #pragma unroll
      for (int i = 0; i < 4; ++i) {
        As[i] = S[(size_t)((t8 << 3) + 8 + i) * 64];
        Au[i] = U[(size_t)((t8 << 3) + 8 + i) * 64];
      }
    }
    PROCESS4((t8 << 3));
    #pragma unroll
    for (int i = 0; i < 4; ++i) { cs[i] = Bs[i]; cu[i] = Bu[i]; }
    if (t8 < TD / 8 - 1) {         // refill B with chunk 2*t8+3
      #pragma unroll
      for (int i = 0; i < 4; ++i) {
        Bs[i] = S[(size_t)((t8 << 3) + 12 + i) * 64];
        Bu[i] = U[(size_t)((t8 << 3) + 12 + i) * 64];
      }
    }
    PROCESS4((t8 << 3) + 4);
  }
}

// ---------------------------------------------------------------------------

extern "C" void kernel_launch(void* const* d_in, const int* in_sizes, int n_in,
                              void* d_out, int out_size, void* d_ws, size_t ws_size,
                              hipStream_t stream) {
  const float* x  = (const float*)d_in[0];
  const float* Ws = (const float*)d_in[1];
  const float* Wb = (const float*)d_in[2];
  const float* Wa = (const float*)d_in[3];

  float* soma_ws = (float*)d_ws;
  float* u_ws    = soma_ws + (size_t)BD * TD * OD;   // +33554432 floats
  float* out     = (float*)d_out;

  dim3 gA(256, 32, 1);   // 256 m-groups x 32 o-groups; block = 8 waves = 8 o-cols
  proj_kernel<<<gA, 512, 0, stream>>>(x, Ws, Wb, Wa, soma_ws, u_ws);
  dyn_kernel<<<4, 512, 0, stream>>>(soma_ws, u_ws, out);
}

// Round 5
// 4815.451 us; speedup vs baseline: 1.8165x; 1.3904x over previous
//
#include <hip/hip_runtime.h>
#include <cstdint>
#include <cstddef>

#define BD 32
#define TD 4096
#define ID 256
#define OD 256

// f32 constants, computed in f64 and rounded (matches np.exp on f32 within <=1 ulp)
#define A_DEND 0.90483741803595957f   // exp(-1/10)
#define A_SYN  0.81873075307798182f   // exp(-1/5)
#define A_MEM  0.95122942450071402f   // exp(-1/20)
#define TWO_PI_F 6.28318530717958647692f
#define BASE_DTH 62.8318530717958647692f  // 2*pi*10
#define INV256 0.00390625f

#define DOT4(acc, xv, wv)               \
  acc = fmaf((xv).x, (wv).x, acc);      \
  acc = fmaf((xv).y, (wv).y, acc);      \
  acc = fmaf((xv).z, (wv).z, acc);      \
  acc = fmaf((xv).w, (wv).w, acc);

// direct global->LDS DMA, width 16 B (dest = wave-uniform base + lane*16)
__device__ __forceinline__ void gload_lds16(const float* g, float* l) {
  __builtin_amdgcn_global_load_lds(
      (const __attribute__((address_space(1))) unsigned int*)g,
      (__attribute__((address_space(3))) unsigned int*)l,
      16, 0, 0);
}

// ---------------------------------------------------------------------------
// Phase A v4: all-LDS (round-1 scheme) rebalanced to R=8 rows x C=1 col.
// Per 4-k step a wave issues 8 x-reads + 7 w-reads (15 b128) for 224 fmac
// -> LDS pipe (4*15*8 = 480 cyc/CU) ~= VALU (448 cyc/SIMD): balanced, vs
// round-1's 2.6x LDS overload. Registers by construction ~105 (acc 56 +
// xv 32 + w 4) -> no spill even at a 128 budget (round-2 lesson).
// Block = 512 thr (16 oo x 32 mg), owns 16 o-cols x 256 m-rows. Weights
// staged once (112 rows x 260-pad = 116 KB, 2-way reads = free); x streamed
// as 16-k chunks (2 x 16 KB double-buffer). ALL staging via global_load_lds
// width=16: dest is exactly wave-uniform + lane*16 for both w and x.
// Lane rows = mg+32r -> row addresses split bank halves (2-way = free).
// Accumulation: k-ascending fmaf chain + round-1 epilogue expressions ->
// bit-identical output.
// ---------------------------------------------------------------------------

#define WSTR 260   // weight row stride (floats); 1040 B, 16-B aligned, 2-way banks

__global__ __launch_bounds__(512, 1)
void proj_kernel(const float* __restrict__ x,
                 const float* __restrict__ Ws,
                 const float* __restrict__ Wb,
                 const float* __restrict__ Wa,
                 float* __restrict__ soma_ws,
                 float* __restrict__ u_ws) {
  #pragma clang fp contract(off)
  __shared__ float wl[112 * WSTR];   // 116,480 B
  __shared__ float xsf[2 * 4096];    //  32,768 B  (2 bufs x 256 rows x 16 k)

  const int tid = threadIdx.x;
  const int l   = tid & 63;
  const int w   = tid >> 6;          // wave id 0..7

  // bijective XCD-aware mapping: 16 o-blocks of one m-slab -> same XCD
  // (assumes bid%8 round-robin; wrong assumption costs only locality)
  const int bid    = (int)blockIdx.x;          // 0..8191
  const int slot   = bid >> 3;                 // 0..1023
  const int family = ((slot >> 4) << 3) + (bid & 7);   // m-slab 0..511
  const int within = slot & 15;                // o-group 0..15
  const int o0     = within << 4;
  const int slab0  = family << 8;              // first m-row (x256)

  // ---- stage weights via global_load_lds: rep r = rep*8+w is wave-uniform,
  //      dest wl + r*260 + lane*4 floats == uniform base + lane*16 B ----
  #pragma unroll
  for (int rep = 0; rep < 14; ++rep) {
    const int r = (rep << 3) + w;    // 0..111, uniform per wave
    const float* src;
    if (r < 16) {
      src = Ws + (((size_t)(o0 + r)) << 8);
    } else if (r < 80) {
      src = Wb + (((size_t)((((r - 16) >> 4) << 8) + o0 + (r & 15))) << 8);
    } else {
      src = Wa + (((size_t)((((r - 80) >> 4) << 8) + o0 + (r & 15))) << 8);
    }
    gload_lds16(src + (l << 2), wl + r * WSTR);
  }

  // x chunk staging geometry: chunk = 256 rows x 16 k = 1024 float4;
  // thread covers f = tid and tid+512; row = f>>2, kq = f&3.
  const float4* g0 = (const float4*)x + ((size_t)(slab0 + (tid >> 2)) << 6) + (tid & 3);
  const float4* g1 = g0 + (128 << 6);          // rows +128
  const int wb4 = ((tid >> 6) << 6) << 2;      // wave base, floats (w*64 float4)
  // stage chunk 0 -> buf 0
  gload_lds16((const float*)g0, xsf + wb4);
  gload_lds16((const float*)g1, xsf + wb4 + 2048);

  const int oo = tid & 15;
  const int mg = tid >> 4;                     // 0..31
  const float* wA = wl + oo * WSTR;            // p = 0..3 via +p*4160 floats
  const float* wB = wA + 4 * 16 * WSTR;        // p = 4..6
  const float* xbf = xsf + (mg << 4);          // + r*512 + q*4 (+4096 for buf1)

  float acc[7][8];
  #pragma unroll
  for (int p = 0; p < 7; ++p) {
    #pragma unroll
    for (int r = 0; r < 8; ++r) acc[p][r] = 0.f;
  }

  __syncthreads();   // drains all staging DMAs (vmcnt) + joins waves

#define K4GROUP(XOFF, WOFF)                                                \
  _Pragma("unroll")                                                        \
  for (int q = 0; q < 4; ++q) {                                            \
    float4 xv[8];                                                          \
    _Pragma("unroll")                                                      \
    for (int r = 0; r < 8; ++r)                                            \
      xv[r] = *(const float4*)(xbf + (XOFF) + r * 512 + (q << 2));         \
    _Pragma("unroll")                                                      \
    for (int p = 0; p < 7; ++p) {                                          \
      const float* wp = (p < 4) ? (wA + p * 16 * WSTR)                     \
                                : (wB + (p - 4) * 16 * WSTR);              \
      float4 wv = *(const float4*)(wp + (WOFF) + (q << 2));                \
      DOT4(acc[p][0], xv[0], wv) DOT4(acc[p][1], xv[1], wv)                \
      DOT4(acc[p][2], xv[2], wv) DOT4(acc[p][3], xv[3], wv)                \
      DOT4(acc[p][4], xv[4], wv) DOT4(acc[p][5], xv[5], wv)                \
      DOT4(acc[p][6], xv[6], wv) DOT4(acc[p][7], xv[7], wv)                \
    }                                                                      \
  }

  for (int c = 0; c < 8; ++c) {
    // chunk 2c: compute buf0, prefetch chunk 2c+1 -> buf1
    gload_lds16((const float*)(g0 + 4), xsf + 4096 + wb4);
    gload_lds16((const float*)(g1 + 4), xsf + 4096 + wb4 + 2048);
    K4GROUP(0, 0)
    __syncthreads();
    // chunk 2c+1: compute buf1, prefetch chunk 2c+2 -> buf0
    if (c < 7) {
      gload_lds16((const float*)(g0 + 8), xsf + wb4);
      gload_lds16((const float*)(g1 + 8), xsf + wb4 + 2048);
    }
    K4GROUP(4096, 16)
    __syncthreads();
    wA += 32; wB += 32; g0 += 8; g1 += 8;   // advance k by 32 floats / 8 float4
  }

  // epilogue: identical expressions/roundings to the round-1 passing kernel
  #pragma unroll
  for (int r = 0; r < 8; ++r) {
    const size_t off = (((size_t)slab0 + mg + (r << 5)) << 8) + o0 + oo;
    float bm = ((fmaxf(acc[1][r], 0.f) + fmaxf(acc[2][r], 0.f)) +
                (fmaxf(acc[3][r], 0.f) + fmaxf(acc[4][r], 0.f))) * 0.25f;
    float am = (fmaxf(acc[5][r], 0.f) + fmaxf(acc[6][r], 0.f)) * 0.5f;
    soma_ws[off] = acc[0][r];
    u_ws[off]    = bm + am;
  }
}

// ---------------------------------------------------------------------------
// Phase B: sequential LIF + Kuramoto. REVERTED to the round-1-verified
// geometry (32 blocks x 1 wave, ~1378 us): the 512-thread variants regressed
// ~2x in rounds 2-3 for reasons not yet isolated by counters (dyn never
// appeared in top-5). With proj now ~1 ms, dyn becomes the top dispatch and
// gets profiled next round. Lane owns o=4l..4l+3; DPP wave64 sums; depth-2
// (A/B) prefetch; spike=(v>0) is bit-identical to sg+(hh-sg) in f32.
// ---------------------------------------------------------------------------

#define DPP_ADD(v, ctrl, rm, bm, bc)                                          \
  v += __builtin_bit_cast(float, __builtin_amdgcn_update_dpp(                 \
           0, __builtin_bit_cast(int, v), ctrl, rm, bm, bc));

__device__ __forceinline__ float wave_sum64(float v) {
  DPP_ADD(v, 0x111, 0xf, 0xf, true)    // row_shr:1
  DPP_ADD(v, 0x112, 0xf, 0xf, true)    // row_shr:2
  DPP_ADD(v, 0x114, 0xf, 0xf, true)    // row_shr:4
  DPP_ADD(v, 0x118, 0xf, 0xf, true)    // row_shr:8
  DPP_ADD(v, 0x142, 0xa, 0xf, false)   // row_bcast:15 -> rows 1,3
  DPP_ADD(v, 0x143, 0xc, 0xf, false)   // row_bcast:31 -> rows 2,3
  return __builtin_bit_cast(float, __builtin_amdgcn_readlane(__builtin_bit_cast(int, v), 63));
}

#define PROCESS4(TBASE)                                                       \
  _Pragma("unroll")                                                           \
  for (int i = 0; i < 4; ++i) {                                               \
    const int t = (TBASE) + i;                                                \
    const float* sv = &cs[i].x;                                               \
    const float* uv = &cu[i].x;                                               \
    float spk[4], cc[4], ss[4];                                               \
    _Pragma("unroll")                                                         \
    for (int j = 0; j < 4; ++j) {                                             \
      float t1 = A_DEND * dend[j];                                            \
      float t2 = bD * uv[j];                                                  \
      dend[j] = t1 + t2;                                                      \
      float drive = sv[j] + 0.5f * dend[j];                                   \
      syn[j] = (A_SYN * syn[j]) + drive;                                      \
      mem[j] = (A_MEM * mem[j]) + syn[j];                                     \
      float v = mem[j] - 1.0f;                                                \
      float sp = (v > 0.0f) ? 1.0f : 0.0f;                                    \
      mem[j] = mem[j] - sp;                                                   \
      spk[j] = sp;                                                            \
      cc[j] = __cosf(th[j]);                                                  \
      ss[j] = __sinf(th[j]);                                                  \
    }                                                                         \
    float csum = (cc[0] + cc[1]) + (cc[2] + cc[3]);                           \
    float ssum = (ss[0] + ss[1]) + (ss[2] + ss[3]);                           \
    float cS = wave_sum64(csum);                                              \
    float sS = wave_sum64(ssum);                                              \
    _Pragma("unroll")                                                         \
    for (int j = 0; j < 4; ++j) {                                             \
      float coup = (sS * cc[j] - cS * ss[j]) * INV256;                        \
      float dth = (BASE_DTH + coup) + spk[j];                                 \
      th[j] = th[j] + 0.001f * dth;                                           \
      th[j] = (th[j] >= TWO_PI_F) ? (th[j] - TWO_PI_F) : th[j];               \
    }                                                                         \
    float4 so = {spk[0], spk[1], spk[2], spk[3]};                             \
    float4 po = {th[0], th[1], th[2], th[3]};                                 \
    float4 mo = {mem[0], mem[1], mem[2], mem[3]};                             \
    Os[(size_t)t * 64] = so;                                                  \
    Op[(size_t)t * 64] = po;                                                  \
    Om[(size_t)t * 64] = mo;                                                  \
  }

__global__ __launch_bounds__(64, 1)
void dyn_kernel(const float* __restrict__ soma_ws,
                const float* __restrict__ u_ws,
                float* __restrict__ out) {
  // Match numpy's per-op rounding: no mul+add fusion except explicit fmaf.
  #pragma clang fp contract(off)
  const int b = blockIdx.x;
  const int l = threadIdx.x;

  const size_t base4 = ((size_t)b << 18) + l;        // float4 units
  const float4* S = (const float4*)soma_ws + base4;
  const float4* U = (const float4*)u_ws + base4;
  float4* Os = (float4*)out + base4;                 // spikes
  float4* Op = Os + ((size_t)1 << 23);               // phases
  float4* Om = Op + ((size_t)1 << 23);               // membrane

  float dend[4] = {0.f, 0.f, 0.f, 0.f};
  float syn[4]  = {0.f, 0.f, 0.f, 0.f};
  float mem[4]  = {0.f, 0.f, 0.f, 0.f};
  float th[4]   = {0.f, 0.f, 0.f, 0.f};

  const float bD = 1.0f - A_DEND;   // exact (Sterbenz)

  float4 As[4], Au[4], Bs[4], Bu[4];
  #pragma unroll
  for (int i = 0; i < 4; ++i) { As[i] = S[(size_t)i * 64];       Au[i] = U[(size_t)i * 64]; }
  #pragma unroll
  for (int i = 0; i < 4; ++i) { Bs[i] = S[(size_t)(4 + i) * 64]; Bu[i] = U[(size_t)(4 + i) * 64]; }

  for (int t8 = 0; t8 < TD / 8; ++t8) {
    float4 cs[4], cu[4];
    #pragma unroll
    for (int i = 0; i < 4; ++i) { cs[i] = As[i]; cu[i] = Au[i]; }
    if (t8 < TD / 8 - 1) {         // refill A with chunk 2*t8+2
      #pragma unroll
      for (int i = 0; i < 4; ++i) {
        As[i] = S[(size_t)((t8 << 3) + 8 + i) * 64];
        Au[i] = U[(size_t)((t8 << 3) + 8 + i) * 64];
      }
    }
    PROCESS4((t8 << 3));
    #pragma unroll
    for (int i = 0; i < 4; ++i) { cs[i] = Bs[i]; cu[i] = Bu[i]; }
    if (t8 < TD / 8 - 1) {         // refill B with chunk 2*t8+3
      #pragma unroll
      for (int i = 0; i < 4; ++i) {
        Bs[i] = S[(size_t)((t8 << 3) + 12 + i) * 64];
        Bu[i] = U[(size_t)((t8 << 3) + 12 + i) * 64];
      }
    }
    PROCESS4((t8 << 3) + 4);
  }
}

// ---------------------------------------------------------------------------

extern "C" void kernel_launch(void* const* d_in, const int* in_sizes, int n_in,
                              void* d_out, int out_size, void* d_ws, size_t ws_size,
                              hipStream_t stream) {
  const float* x  = (const float*)d_in[0];
  const float* Ws = (const float*)d_in[1];
  const float* Wb = (const float*)d_in[2];
  const float* Wa = (const float*)d_in[3];

  float* soma_ws = (float*)d_ws;
  float* u_ws    = soma_ws + (size_t)BD * TD * OD;   // +33554432 floats
  float* out     = (float*)d_out;

  proj_kernel<<<8192, 512, 0, stream>>>(x, Ws, Wb, Wa, soma_ws, u_ws);
  dyn_kernel<<<BD, 64, 0, stream>>>(soma_ws, u_ws, out);
}